// Round 7
// baseline (185.762 us; speedup 1.0000x reference)
//
#include <hip/hip_runtime.h>

// out[b, i] = in[b, perm[i]]  for b in [0, 131072), i in [0, 1024), fp32.
//
// R6 kernel (proven 184.0 us, 5.83 TB/s) + ONE change: persistent grid of
// 1280 blocks (5 blocks/CU x 256 CU, LDS-limited residency) instead of 4096.
// Eliminates block launch/drain churn and residency-generation tail; each
// wave runs ~25 iterations.
//
//  - nontemporal global loads/stores (L2 bypass — the R6 win)
//  - wave-private LDS staging, ZERO barriers (in-order per-wave DS pipe)
//  - 2 rows per wave-iteration, 8 float4 loads in flight
//  - perm indices register-resident (int4 x4 per lane)
//  - all global accesses 16 B/lane coalesced

#define NCOLS 1024
#define THREADS 256
#define WPB 4   // waves per block

typedef float f4 __attribute__((ext_vector_type(4)));

__global__ __launch_bounds__(THREADS) void
permute_rows_nt(const float* __restrict__ in,
                const int* __restrict__ perm,
                float* __restrict__ out,
                int batch)
{
    __shared__ float buf[WPB][2][NCOLS];   // 32 KB per block
    const int w = threadIdx.x >> 6;
    const int l = threadIdx.x & 63;

    // 16 gather indices per lane.
    int4 p[4];
#pragma unroll
    for (int k = 0; k < 4; ++k)
        p[k] = *reinterpret_cast<const int4*>(perm + 256 * k + 4 * l);

    const int gw = blockIdx.x * WPB + w;    // global wave id
    const int nw = gridDim.x * WPB;         // total waves

    float* const s0 = buf[w][0];
    float* const s1 = buf[w][1];

    for (int b = gw; b < batch; b += 2 * nw) {
        const int b2 = b + nw;
        const bool has2 = (b2 < batch);

        // ---- issue all global loads for both rows (nontemporal) ----
        const float* __restrict__ r0 = in + (size_t)b * NCOLS;
        const float* __restrict__ r1 = in + (size_t)(has2 ? b2 : b) * NCOLS;
        f4 v0[4], v1[4];
#pragma unroll
        for (int k = 0; k < 4; ++k)
            v0[k] = __builtin_nontemporal_load(
                        reinterpret_cast<const f4*>(r0 + 256 * k + 4 * l));
#pragma unroll
        for (int k = 0; k < 4; ++k)
            v1[k] = __builtin_nontemporal_load(
                        reinterpret_cast<const f4*>(r1 + 256 * k + 4 * l));

        // ---- stage into this wave's private LDS ----
#pragma unroll
        for (int k = 0; k < 4; ++k)
            *reinterpret_cast<f4*>(s0 + 256 * k + 4 * l) = v0[k];
#pragma unroll
        for (int k = 0; k < 4; ++k)
            *reinterpret_cast<f4*>(s1 + 256 * k + 4 * l) = v1[k];

        // ---- gather (wave-synchronous) ----
        f4 o0[4], o1[4];
#pragma unroll
        for (int k = 0; k < 4; ++k) {
            o0[k].x = s0[p[k].x];
            o0[k].y = s0[p[k].y];
            o0[k].z = s0[p[k].z];
            o0[k].w = s0[p[k].w];
        }
#pragma unroll
        for (int k = 0; k < 4; ++k) {
            o1[k].x = s1[p[k].x];
            o1[k].y = s1[p[k].y];
            o1[k].z = s1[p[k].z];
            o1[k].w = s1[p[k].w];
        }

        // ---- coalesced nontemporal stores ----
        float* __restrict__ q0 = out + (size_t)b * NCOLS;
#pragma unroll
        for (int k = 0; k < 4; ++k)
            __builtin_nontemporal_store(
                o0[k], reinterpret_cast<f4*>(q0 + 256 * k + 4 * l));
        if (has2) {
            float* __restrict__ q1 = out + (size_t)b2 * NCOLS;
#pragma unroll
            for (int k = 0; k < 4; ++k)
                __builtin_nontemporal_store(
                    o1[k], reinterpret_cast<f4*>(q1 + 256 * k + 4 * l));
        }
    }
}

extern "C" void kernel_launch(void* const* d_in, const int* in_sizes, int n_in,
                              void* d_out, int out_size, void* d_ws, size_t ws_size,
                              hipStream_t stream)
{
    const float* features = (const float*)d_in[0];
    const int*   perm     = (const int*)d_in[1];
    float*       out      = (float*)d_out;

    const int batch = out_size / NCOLS;   // 131072

    // Persistent: 5 blocks/CU (32 KB LDS each of 160 KB) x 256 CU.
    const int grid = 1280;
    permute_rows_nt<<<grid, THREADS, 0, stream>>>(features, perm, out, batch);
}